// Round 5
// baseline (378.635 us; speedup 1.0000x reference)
//
#include <hip/hip_runtime.h>

#define BB  65536
#define INW 128
#define HH  256
#define MM  32
#define KK  (INW + HH)   // 384
#define NKC 12           // 32-wide K chunks in the main GEMM

typedef __attribute__((ext_vector_type(8))) short bf16x8;
typedef __attribute__((ext_vector_type(4))) float f32x4;

__device__ __forceinline__ unsigned short f32_to_bf16(float f) {
    union { float f; unsigned u; } v; v.f = f;
    return (unsigned short)((v.u + 0x7fffu + ((v.u >> 16) & 1u)) >> 16);
}

__device__ __forceinline__ bf16x8 cvt8(f32x4 a, f32x4 b) {
    bf16x8 r;
    r[0] = (short)f32_to_bf16(a[0]); r[1] = (short)f32_to_bf16(a[1]);
    r[2] = (short)f32_to_bf16(a[2]); r[3] = (short)f32_to_bf16(a[3]);
    r[4] = (short)f32_to_bf16(b[0]); r[5] = (short)f32_to_bf16(b[1]);
    r[6] = (short)f32_to_bf16(b[2]); r[7] = (short)f32_to_bf16(b[3]);
    return r;
}

__device__ __forceinline__ float rcp_f(float x) { return __builtin_amdgcn_rcpf(x); }
__device__ __forceinline__ float sigmoid_f(float x) { return rcp_f(1.0f + __expf(-x)); }
__device__ __forceinline__ float tanh_f(float x) { return 1.0f - 2.0f * rcp_f(__expf(2.0f * x) + 1.0f); }

// ---- weight fp32 -> bf16, packed fragment-major (unchanged layout) ----
// Wi_p: [half][kc][t][512], Wm_p: [half][t][512]; fragment = 512 bf16 = 1KB.
__global__ void pack_weights(const float* __restrict__ Wi, const float* __restrict__ Wm,
                             unsigned short* __restrict__ Wi_p, unsigned short* __restrict__ Wm_p) {
    int id = blockIdx.x * 256 + threadIdx.x;
    if (id < 2 * NKC * 8 * 512) {
        int blk = id >> 9;
        int e   = id & 511;
        int lane = e >> 3, j = e & 7;
        int lrow = lane & 15, quad = lane >> 4;
        int h  = blk / (NKC * 8);
        int b  = blk % (NKC * 8);
        int kc = b >> 3;
        int t  = b & 7;
        int n  = h * 128 + t * 16 + lrow;
        int k  = kc * 32 + quad * 8 + j;
        Wi_p[id] = f32_to_bf16(Wi[(size_t)n * KK + k]);
    }
    if (id < 2 * 8 * 512) {
        int blk = id >> 9;
        int e   = id & 511;
        int lane = e >> 3, j = e & 7;
        int lrow = lane & 15, quad = lane >> 4;
        int h = blk >> 3;
        int t = blk & 7;
        int n = h * 128 + t * 16 + lrow;
        Wm_p[id] = f32_to_bf16(Wm[(size_t)n * MM + quad * 8 + j]);
    }
}

// ---- epilogue math for one tile t: 4 outputs per lane ----
__device__ __forceinline__ void epilogue4(f32x4 g4, f32x4 am, f32x4 ct4, f32x4 bi4, f32x4 bm4,
                                          float* __restrict__ p, size_t outH) {
    f32x4 h4, c4;
#pragma unroll
    for (int r = 0; r < 4; ++r) {
        float g    = g4[r] + bi4[r];
        float mp   = am[r] + bm4[r];
        float gate = sigmoid_f(g);
        float tg   = tanh_f(g);
        float c    = ct4[r] * gate + tg * gate;
        float cr   = tanh_f(c);
        float mg   = sigmoid_f(mp);
        float cf   = c - cr + cr * mg;
        float h    = tanh_f(cf) * gate;
        h4[r] = h; c4[r] = c;
    }
    __builtin_nontemporal_store(h4, (f32x4*)p);
    __builtin_nontemporal_store(h4, (f32x4*)(p + outH));
    __builtin_nontemporal_store(c4, (f32x4*)(p + 2 * outH));
}

// ---- fused RLSTM: persistent barrier-free waves, LDS-resident weights ----
// Grid = 512 blocks x 512 thr (8 waves) = exactly 2 blocks/CU (16 waves/CU,
// 2x round-4 TLP). Weights staged to LDS ONCE; a single __syncthreads ever;
// the 4-iteration work loop has NO sync points, so waves desynchronize and
// the CU keeps a continuous stream of outstanding loads (TLP covers the
// compiler's per-wave MLP cap of ~4 that rounds 1-4 could not raise).
// Work map keeps XCD colocation (round 4: FETCH 247->87 MB): blocks with
// b&7==k run on XCD k; the 4 n-quarters of each rowblock are processed on
// the same XCD at the same iteration -> acts fetched from HBM once.
__global__ __launch_bounds__(512, 4) void rlstm_main(
    const float* __restrict__ input, const float* __restrict__ media,
    const float* __restrict__ h_t,   const float* __restrict__ c_t,
    const unsigned short* __restrict__ Wi_p, const float* __restrict__ bi,
    const unsigned short* __restrict__ Wm_p, const float* __restrict__ bm,
    float* __restrict__ out)
{
    __shared__ unsigned short wiq[NKC * 4 * 512];   // 48 KB: [kc][t'][512]
    __shared__ unsigned short wmq[4 * 512];         // 4 KB:  [t'][512]
    __shared__ float lbi[64], lbm[64];

    const int tid  = threadIdx.x;
    const int wave = tid >> 6;          // 0..7
    const int lane = tid & 63;
    const int lrow = lane & 15;
    const int quad = lane >> 4;

    const int b = blockIdx.x;           // 512 blocks
    const int k = b & 7;                // hw XCD (round-robin dispatch)
    const int j = b >> 3;               // 0..63 within XCD
    const int q = j & 3;                // n-quarter (fixed per block)
    const int g = j >> 2;               // 0..15 row-group lane
    const int half  = q >> 1;
    const int thalf = q & 1;
    const int n0q   = q * 64;

    // ---- stage this block's weight quarter into LDS (once per kernel) ----
#pragma unroll
    for (int r = 0; r < 6; ++r) {
        int le  = (r * 512 + tid) * 8;
        int kc  = le >> 11;
        int rem = le & 2047;
        *(bf16x8*)(wiq + le) =
            *(const bf16x8*)(Wi_p + (size_t)(half * NKC + kc) * 4096 + thalf * 2048 + rem);
    }
    if (tid < 256) {
        int le = tid * 8;
        *(bf16x8*)(wmq + le) =
            *(const bf16x8*)(Wm_p + (size_t)half * 4096 + thalf * 2048 + le);
    }
    if (tid < 64)        lbi[tid]      = bi[n0q + tid];
    else if (tid < 128)  lbm[tid - 64] = bm[n0q + (tid - 64)];
    __syncthreads();                    // the ONLY barrier in this kernel

    const size_t outH = (size_t)BB * HH;

    // ---- persistent work loop: 4 rowblocks per block, no barriers ----
#pragma unroll
    for (int it = 0; it < 4; ++it) {
        const int rowblk = k * 64 + g * 4 + it;          // XCD-colocated
        const int arow   = rowblk * 128 + wave * 16 + lrow;
        const size_t rb  = (size_t)arow * HH + n0q;

        // load burst: 24 act + 4 c_t + 2 media vector loads
        f32x4 a[24];
#pragma unroll
        for (int kc = 0; kc < NKC; ++kc) {
            const float* s = (kc < 4) ? input + (size_t)arow * INW + kc * 32 + quad * 8
                                      : h_t   + (size_t)arow * HH  + (kc - 4) * 32 + quad * 8;
            a[2 * kc]     = ((const f32x4*)s)[0];
            a[2 * kc + 1] = ((const f32x4*)s)[1];
        }
        f32x4 ct[4];
#pragma unroll
        for (int t = 0; t < 4; ++t)
            ct[t] = *(const f32x4*)(c_t + rb + t * 16 + quad * 4);
        f32x4 md0 = *(const f32x4*)(media + (size_t)arow * MM + quad * 8);
        f32x4 md1 = *(const f32x4*)(media + (size_t)arow * MM + quad * 8 + 4);

        // GEMM: weights from LDS (lgkmcnt path), acts from regs
        f32x4 acc[4];
#pragma unroll
        for (int t = 0; t < 4; ++t) acc[t] = (f32x4){0.f, 0.f, 0.f, 0.f};
#pragma unroll
        for (int kc = 0; kc < NKC; ++kc) {
            bf16x8 xa = cvt8(a[2 * kc], a[2 * kc + 1]);
#pragma unroll
            for (int t = 0; t < 4; ++t) {
                bf16x8 wf = *(const bf16x8*)(wiq + kc * 2048 + t * 512 + lane * 8);
                acc[t] = __builtin_amdgcn_mfma_f32_16x16x32_bf16(wf, xa, acc[t], 0, 0, 0);
            }
        }

        // epilogue
        bf16x8 mf = cvt8(md0, md1);
#pragma unroll
        for (int t = 0; t < 4; ++t) {
            bf16x8 wmf = *(const bf16x8*)(wmq + t * 512 + lane * 8);
            f32x4 am = __builtin_amdgcn_mfma_f32_16x16x32_bf16(
                wmf, mf, (f32x4){0.f, 0.f, 0.f, 0.f}, 0, 0, 0);
            const int nb = t * 16 + quad * 4;
            f32x4 bi4 = *(const f32x4*)(lbi + nb);
            f32x4 bm4 = *(const f32x4*)(lbm + nb);
            epilogue4(acc[t], am, ct[t], bi4, bm4, out + rb + nb, outH);
        }
    }
}

extern "C" void kernel_launch(void* const* d_in, const int* in_sizes, int n_in,
                              void* d_out, int out_size, void* d_ws, size_t ws_size,
                              hipStream_t stream) {
    const float* input = (const float*)d_in[0];
    const float* media = (const float*)d_in[1];
    const float* h_t   = (const float*)d_in[2];
    const float* c_t   = (const float*)d_in[3];
    const float* Wi    = (const float*)d_in[4];
    const float* bi    = (const float*)d_in[5];
    const float* Wm    = (const float*)d_in[6];
    const float* bm    = (const float*)d_in[7];
    float* out = (float*)d_out;

    unsigned short* Wi_p = (unsigned short*)d_ws;
    unsigned short* Wm_p = Wi_p + 2 * NKC * 8 * 512;

    hipLaunchKernelGGL(pack_weights, dim3((2 * NKC * 8 * 512 + 255) / 256), dim3(256), 0, stream,
                       Wi, Wm, Wi_p, Wm_p);
    // persistent grid: 512 blocks of 512 threads = 2 blocks/CU exactly
    hipLaunchKernelGGL(rlstm_main, dim3(512), dim3(512), 0, stream,
                       input, media, h_t, c_t, Wi_p, bi, Wm_p, bm, out);
}